// Round 9
// baseline (334.929 us; speedup 1.0000x reference)
//
#include <hip/hip_runtime.h>
#include <math.h>

#define H   1024
#define NH  16
#define DH  64
#define BB  4
#define SS  2048
#define M_ROWS (BB*SS)   // 8192
#define EPS 1e-12f
// 0.125 (=1/sqrt(DH)) * log2(e): scores come out in log2 domain -> raw v_exp_f32
#define QSCALE 0.18033688011112042f

typedef __attribute__((ext_vector_type(4))) float f32x4;
typedef __attribute__((ext_vector_type(8))) short bf16x8;
typedef const __attribute__((address_space(1))) void* as1cvp;
typedef __attribute__((address_space(3))) void*       as3vp;
typedef const __attribute__((address_space(1))) ushort* as1u;
typedef __attribute__((address_space(3))) ushort*       as3u;

__device__ __forceinline__ unsigned short f2bf(float f) {
    union { float f; unsigned u; } x; x.f = f;
    unsigned r = x.u + 0x7fffu + ((x.u >> 16) & 1u);   // RNE
    return (unsigned short)(r >> 16);
}
// pack two floats to packed bf16 (truncate) in ONE v_perm_b32
__device__ __forceinline__ unsigned pk2bf(float lo, float hi) {
    return __builtin_amdgcn_perm(__float_as_uint(hi), __float_as_uint(lo), 0x07060302u);
}

// ---------------------------------------------------------------------------
// Fused fp32 -> bf16 convert for x + all 4 weights. Grid exactly 12288 blocks.
// ---------------------------------------------------------------------------
__global__ __launch_bounds__(256)
void cvt_all(const float4* __restrict__ x,
             const float4* __restrict__ wq, const float4* __restrict__ wk,
             const float4* __restrict__ wv, const float4* __restrict__ wo,
             ushort4* __restrict__ xb, ushort4* __restrict__ wqb,
             ushort4* __restrict__ wkb, ushort4* __restrict__ wvb,
             ushort4* __restrict__ wob)
{
    int id = blockIdx.x * 256 + threadIdx.x;
    const float4* src; ushort4* dst; int off;
    if (id < 2097152) { src = x; dst = xb; off = id; }
    else {
        int t = id - 2097152, wsel = t >> 18;
        off = t & 262143;
        src = wsel == 0 ? wq : wsel == 1 ? wk : wsel == 2 ? wv : wo;
        dst = wsel == 0 ? wqb : wsel == 1 ? wkb : wsel == 2 ? wvb : wob;
    }
    float4 v = src[off];
    ushort4 o; o.x = f2bf(v.x); o.y = f2bf(v.y); o.z = f2bf(v.z); o.w = f2bf(v.w);
    dst[off] = o;
}

// ---------------------------------------------------------------------------
// GEMM core v5: A LDS-staged (3 buffers, counted vmcnt); B DIRECT FROM L2.
// R7/R8 showed the core latency-bound at 27% MfmaUtil with only 41% combined
// issue. B (weights, 2 MB/slice) is L2-resident: fragment loads go straight
// global->VGPR, software-pipelined one K-step ahead with compiler-managed
// waits — no barrier coupling, no LDS round-trip. A keeps the 3-buffer
// counted-vmcnt pipeline (LDS now 24 KB).
// Queue composition per wave at the iter-top wait (steady state):
//   [A_n(2), B_{n-1}(4), A_{n+1}(2), B_n(4)]  ->  vmcnt(6) guarantees A_n
// landed (exactly 6 newer ops) while A_{n+1} + B_n stay in flight. Inline-asm
// memory clobber pins B loads below the wait, so the composition holds.
// Tail: last iter waits vmcnt(0). WAR gap (stage n+2 vs reads at n-1) is one
// barrier, same as R8 (verified).
// ---------------------------------------------------------------------------
#define STAGE_A(ofs, k0)                                                                \
    __builtin_amdgcn_global_load_lds((as1cvp)(gA + gAr0 + (k0)),                        \
                                     (as3vp)(lds + (ofs) + dA0), 16, 0, 0);             \
    __builtin_amdgcn_global_load_lds((as1cvp)(gA + gAr1 + (k0)),                        \
                                     (as3vp)(lds + (ofs) + dA1), 16, 0, 0);

__device__ __forceinline__ void gemm_core_128(const ushort* __restrict__ A,
                                              const ushort* __restrict__ Wt,
                                              ushort* ldsP,
                                              int row0, int col0, int K,
                                              f32x4 (&acc)[4][4])
{
    const int tid = threadIdx.x, lane = tid & 63, w = tid >> 6;
    const int wr = w >> 1, wc = w & 1, l15 = lane & 15, quad = lane >> 4;
    const int lr = lane >> 2, kc = lane & 3;
    const int qs  = kc ^ ((lr >> 1) & 3);           // A staging source-chunk swizzle
    const int qsw = (quad ^ ((l15 >> 1) & 3)) * 8;  // A fragment-read swizzle (ushorts)

    const as1u gA = (as1u)A;
    const as1u gB = (as1u)Wt;
    as3u lds = (as3u)ldsP;

    const int ra = w * 32 + lr;
    const int rb = ra + 16;
    const size_t gAr0 = (size_t)(row0 + ra) * K + qs * 8;
    const size_t gAr1 = (size_t)(row0 + rb) * K + qs * 8;
    const int dA0 = (w * 2 + 0) * 512;   // wave-uniform LDS dest offsets
    const int dA1 = (w * 2 + 1) * 512;

    // B fragment base offsets (per-lane, L2-resident rows; 64 B contiguous
    // per 4-lane quad group -> 16 cache lines per instruction)
    int bOff[4];
    #pragma unroll
    for (int ct = 0; ct < 4; ++ct)
        bOff[ct] = (col0 + wc * 64 + ct * 16 + l15) * K + quad * 8;

    // prologue: A tiles 0,1 staged (4 loads); B frags for step 0 (4 loads)
    STAGE_A(0, 0);
    STAGE_A(4096, 32);
    bf16x8 bcur[4], bnxt[4];
    #pragma unroll
    for (int ct = 0; ct < 4; ++ct) bcur[ct] = *(const bf16x8*)&gB[bOff[ct]];
    #pragma unroll
    for (int ct = 0; ct < 4; ++ct) bnxt[ct] = bcur[ct];

    int cur = 0;   // ushort offset of current A buffer: 0 / 4096 / 8192
    for (int k0 = 0; k0 < K; k0 += 32) {
        // A tile k0 has exactly 6 newer vmem ops in steady state -> vmcnt(6)
        if (k0 + 32 < K) asm volatile("s_waitcnt vmcnt(6)" ::: "memory");
        else             asm volatile("s_waitcnt vmcnt(0)" ::: "memory");
        __builtin_amdgcn_s_barrier();

        int nxt2 = cur + 8192; if (nxt2 >= 12288) nxt2 -= 12288;  // (cur+2)%3
        if (k0 + 64 < K) { STAGE_A(nxt2, k0 + 64); }
        if (k0 + 32 < K) {
            #pragma unroll
            for (int ct = 0; ct < 4; ++ct)
                bnxt[ct] = *(const bf16x8*)&gB[bOff[ct] + k0 + 32];
        }

        const ushort* AsP = ldsP + cur;
        bf16x8 af[4];
        #pragma unroll
        for (int rt = 0; rt < 4; ++rt)
            af[rt] = *(const bf16x8*)&AsP[(wr * 64 + rt * 16 + l15) * 32 + qsw];
        #pragma unroll
        for (int rt = 0; rt < 4; ++rt)
            #pragma unroll
            for (int ct = 0; ct < 4; ++ct)
                acc[rt][ct] = __builtin_amdgcn_mfma_f32_16x16x32_bf16(af[rt], bcur[ct], acc[rt][ct], 0, 0, 0);

        #pragma unroll
        for (int ct = 0; ct < 4; ++ct) bcur[ct] = bnxt[ct];

        cur += 4096; if (cur == 12288) cur = 0;
    }
}

// ---------------------------------------------------------------------------
// Fused QKV projection, XCD-swizzled 1-D grid (1536 blocks), T1 verified R7
// (FETCH 178 -> 43.6 MB). swz=(lin%8)*192+lin/8; z=swz/512, y=(swz%512)/8,
// x=swz%8.
// ---------------------------------------------------------------------------
__global__ __launch_bounds__(256, 3)
void qkv_gemm(const ushort* __restrict__ xb,
              const ushort* __restrict__ Wqb, const ushort* __restrict__ Wkb,
              const ushort* __restrict__ Wvb,
              const float* __restrict__ bq, const float* __restrict__ bk,
              const float* __restrict__ bv,
              ushort* __restrict__ Qb, ushort* __restrict__ Kb, ushort* __restrict__ Vt)
{
    __shared__ __align__(16) ushort Ls[3 * 4096];   // 24 KB, 3 A-buffers
    const int lin = blockIdx.x;                     // 0..1535
    const int swz = (lin & 7) * 192 + (lin >> 3);   // XCD-contiguous logical id
    const int z   = swz >> 9;                       // 0..2
    const int rem = swz & 511;
    const int row0 = (rem >> 3) * 128;
    const int col0 = (rem & 7) * 128;

    const ushort* Wt  = z == 0 ? Wqb : z == 1 ? Wkb : Wvb;
    const float* bias = z == 0 ? bq  : z == 1 ? bk  : bv;

    f32x4 acc[4][4];
    #pragma unroll
    for (int i = 0; i < 4; ++i)
        #pragma unroll
        for (int j = 0; j < 4; ++j)
            acc[i][j] = (f32x4){0.f, 0.f, 0.f, 0.f};

    gemm_core_128(xb, Wt, Ls, row0, col0, H, acc);

    const int tid = threadIdx.x, lane = tid & 63, w = tid >> 6;
    const int wr = w >> 1, wc = w & 1, l15 = lane & 15, quad = lane >> 4;

    #pragma unroll
    for (int rt = 0; rt < 4; ++rt) {
        const int r0g = row0 + wr * 64 + rt * 16 + quad * 4;
        #pragma unroll
        for (int ct = 0; ct < 4; ++ct) {
            const int c = col0 + wc * 64 + ct * 16 + l15;
            const float bs = bias[c];
            if (z == 0) {
                #pragma unroll
                for (int i = 0; i < 4; ++i)
                    Qb[(size_t)(r0g + i) * H + c] = f2bf((acc[rt][ct][i] + bs) * QSCALE);
            } else if (z == 1) {
                #pragma unroll
                for (int i = 0; i < 4; ++i)
                    Kb[(size_t)(r0g + i) * H + c] = f2bf(acc[rt][ct][i] + bs);
            } else {
                const int bb = r0g >> 11, s0 = r0g & 2047;
                const int hh = c >> 6, dd = c & 63;
                ushort4 o;
                o.x = f2bf(acc[rt][ct][0] + bs);
                o.y = f2bf(acc[rt][ct][1] + bs);
                o.z = f2bf(acc[rt][ct][2] + bs);
                o.w = f2bf(acc[rt][ct][3] + bs);
                *(ushort4*)&Vt[(((size_t)(bb * 16 + hh) * 64 + dd) << 11) + s0] = o;
            }
        }
    }
}

// ---------------------------------------------------------------------------
// O projection: fp32 out + residual. XCD-swizzled 1-D grid (512 blocks).
// ---------------------------------------------------------------------------
__global__ __launch_bounds__(256, 3)
void oproj_gemm(const ushort* __restrict__ ctxb, const ushort* __restrict__ Wob,
                const float* __restrict__ bo, const float* __restrict__ res,
                float* __restrict__ Xr)
{
    __shared__ __align__(16) ushort Ls[3 * 4096];   // 24 KB, 3 A-buffers
    const int lin = blockIdx.x;                     // 0..511
    const int swz = (lin & 7) * 64 + (lin >> 3);
    const int row0 = (swz >> 3) * 128;
    const int col0 = (swz & 7) * 128;

    f32x4 acc[4][4];
    #pragma unroll
    for (int i = 0; i < 4; ++i)
        #pragma unroll
        for (int j = 0; j < 4; ++j)
            acc[i][j] = (f32x4){0.f, 0.f, 0.f, 0.f};

    gemm_core_128(ctxb, Wob, Ls, row0, col0, H, acc);

    const int tid = threadIdx.x, lane = tid & 63, w = tid >> 6;
    const int wr = w >> 1, wc = w & 1, l15 = lane & 15, quad = lane >> 4;

    #pragma unroll
    for (int rt = 0; rt < 4; ++rt) {
        const int r0g = row0 + wr * 64 + rt * 16 + quad * 4;
        #pragma unroll
        for (int ct = 0; ct < 4; ++ct) {
            const int c = col0 + wc * 64 + ct * 16 + l15;
            const float bs = bo[c];
            #pragma unroll
            for (int i = 0; i < 4; ++i) {
                size_t idx = (size_t)(r0g + i) * H + c;
                Xr[idx] = acc[rt][ct][i] + bs + res[idx];
            }
        }
    }
}

// ---------------------------------------------------------------------------
// Flash attention v6 (unchanged from R8): QBLK=64 per wave (4 q-groups),
// in-register P via permuted-K QK^T, l via ones-MFMA, one barrier/iter
// double-buffered K/V tiles. Near combined-issue saturation (~85%).
// ---------------------------------------------------------------------------
#define KTILE 64
#define NKT (SS / KTILE)   // 32

__global__ __launch_bounds__(256, 2)
void flash_attn_mfma(const ushort* __restrict__ Qb, const ushort* __restrict__ Kb,
                     const ushort* __restrict__ Vt, ushort* __restrict__ ctx)
{
    __shared__ __align__(16) ushort Ks[2][KTILE * 64];   // 2 x 8 KB
    __shared__ __align__(16) ushort Vs[2][64 * KTILE];   // 2 x 8 KB

    const int tid  = threadIdx.x;
    const int lane = tid & 63;
    const int w    = tid >> 6;
    const int l15  = lane & 15, quad = lane >> 4;
    const int bh   = blockIdx.x & 63;     // low bits -> same XCD per head
    const int qt   = blockIdx.x >> 6;     // 0..7 (256 q-rows per block)
    const int b    = bh >> 4, h = bh & 15;
    const int row0 = qt * 256 + w * 64;   // wave's 64 q-rows
    const size_t qk_base = (size_t)(b * SS) * H + h * DH;
    const size_t vt_base = (size_t)((b * 16 + h) * 64) * SS;

    const as1u gK = (const as1u)Kb;
    const as1u gV = (const as1u)Vt;

    // ---- staging lane constants: 8 rows x 8 chunks per gload_lds instr ----
    const int srow = lane >> 3;            // 0..7
    const int c8   = lane & 7;
    // f(row) = (row&3) | (((row>>3)&1)<<2); row = w*16 + t*8 + srow
    const int sck0 = c8 ^ ((srow & 3) | (((w * 2 + 0) & 1) << 2));  // t=0
    const int sck1 = c8 ^ ((srow & 3) | (((w * 2 + 1) & 1) << 2));  // t=1

    // ---- fragment-read lane constants (loop-invariant LDS ushort offsets) ----
    const int fL = (l15 & 3) | (((l15 >> 2) & 1) << 2);   // f(r) for K rows
    const int fV = (l15 & 3) | (((l15 >> 3) & 1) << 2);   // f(rv) for V rows
    const int rA = 8 * (l15 >> 2) + (l15 & 3);            // base K row (ct=0)
    int kOff0[4], kOff1[4], vOff0[4], vOff1[4];
    #pragma unroll
    for (int ct = 0; ct < 4; ++ct) {
        const int r = rA + (ct & 1) * 4 + (ct >> 1) * 32;
        kOff0[ct] = r * 64 + ((quad ^ fL) * 8);
        kOff1[ct] = r * 64 + (((4 | quad) ^ fL) * 8);
    }
    #pragma unroll
    for (int dt = 0; dt < 4; ++dt) {
        const int rv = dt * 16 + l15;
        vOff0[dt] = rv * 64 + ((quad ^ fV) * 8);
        vOff1[dt] = rv * 64 + (((4 | quad) ^ fV) * 8);
    }

    // Q fragments for all four q-groups
    bf16x8 aq[4][2];
    #pragma unroll
    for (int g = 0; g < 4; ++g) {
        const size_t qrow = qk_base + (size_t)(row0 + g * 16 + l15) * H;
        aq[g][0] = *(const bf16x8*)&Qb[qrow + quad * 8];
        aq[g][1] = *(const bf16x8*)&Qb[qrow + 32 + quad * 8];
    }

    // all-ones bf16 B-operand for the l rowsum MFMAs
    union { unsigned u[4]; bf16x8 v; } ONES;
    #pragma unroll
    for (int i = 0; i < 4; ++i) ONES.u[i] = 0x3F803F80u;

    f32x4 acc_l[4];
    f32x4 o[4][4];
    #pragma unroll
    for (int g = 0; g < 4; ++g) {
        acc_l[g] = (f32x4){0.f, 0.f, 0.f, 0.f};
        #pragma unroll
        for (int dt = 0; dt < 4; ++dt) o[g][dt] = (f32x4){0.f, 0.f, 0.f, 0.f};
    }

    // hoisted staging base pointers (row = w*16 + srow baked in)
    const as1u gK0 = gK + qk_base + (size_t)(w * 16 + srow) * H;
    const as1u gV0 = gV + vt_base + (size_t)(w * 16 + srow) * SS;

    // ---- stage tile 0 into buffer 0 ----
    __builtin_amdgcn_global_load_lds((as1cvp)(gK0 + sck0 * 8),
                                     (as3vp)(&Ks[0][(w * 16) * 64]), 16, 0, 0);
    __builtin_amdgcn_global_load_lds((as1cvp)(gK0 + (size_t)8 * H + sck1 * 8),
                                     (as3vp)(&Ks[0][(w * 16 + 8) * 64]), 16, 0, 0);
    __builtin_amdgcn_global_load_lds((as1cvp)(gV0 + sck0 * 8),
                                     (as3vp)(&Vs[0][(w * 16) * 64]), 16, 0, 0);
    __builtin_amdgcn_global_load_lds((as1cvp)(gV0 + (size_t)8 * SS + sck1 * 8),
                                     (as3vp)(&Vs[0][(w * 16 + 8) * 64]), 16, 0, 0);

    for (int kt = 0; kt < NKT; ++kt) {
        __syncthreads();   // tile kt landed (issued a full iter ago); prev reads done

        if (kt + 1 < NKT) {
            const int j0 = (kt + 1) * KTILE;
            const int nb = (kt + 1) & 1;
            __builtin_amdgcn_global_load_lds((as1cvp)(gK0 + (size_t)j0 * H + sck0 * 8),
                                             (as3vp)(&Ks[nb][(w * 16) * 64]), 16, 0, 0);
            __builtin_amdgcn_global_load_lds((as1cvp)(gK0 + (size_t)(j0 + 8) * H + sck1 * 8),
                                             (as3vp)(&Ks[nb][(w * 16 + 8) * 64]), 16, 0, 0);
            __builtin_amdgcn_global_load_lds((as1cvp)(gV0 + j0 + sck0 * 8),
                                             (as3vp)(&Vs[nb][(w * 16) * 64]), 16, 0, 0);
            __builtin_amdgcn_global_load_lds((as1cvp)(gV0 + (size_t)8 * SS + j0 + sck1 * 8),
                                             (as3vp)(&Vs[nb][(w * 16 + 8) * 64]), 16, 0, 0);
        }

        const ushort* Ktile = Ks[kt & 1];
        const ushort* Vtile = Vs[kt & 1];

        // ---- QK^T (permuted K rows): K-frags read ONCE, feed 4 q-groups ----
        f32x4 s[4][4];
        __builtin_amdgcn_s_setprio(1);
        #pragma unroll
        for (int ct = 0; ct < 4; ++ct) {
            const bf16x8 k0 = *(const bf16x8*)&Ktile[kOff0[ct]];
            const bf16x8 k1 = *(const bf16x8*)&Ktile[kOff1[ct]];
            #pragma unroll
            for (int g = 0; g < 4; ++g) {
                f32x4 z = (f32x4){0.f, 0.f, 0.f, 0.f};
                z = __builtin_amdgcn_mfma_f32_16x16x32_bf16(k0, aq[g][0], z, 0, 0, 0);
                z = __builtin_amdgcn_mfma_f32_16x16x32_bf16(k1, aq[g][1], z, 0, 0, 0);
                s[g][ct] = z;
            }
        }
        __builtin_amdgcn_s_setprio(0);

        // ---- exp2 + v_perm pack per group: registers become PV A-fragments ----
        union { unsigned u[4]; bf16x8 v; } A[4][2];
        #pragma unroll
        for (int g = 0; g < 4; ++g) {
            #pragma unroll
            for (int ct = 0; ct < 4; ++ct) {
                const float p0 = __builtin_amdgcn_exp2f(s[g][ct][0]);
                const float p1 = __builtin_amdgcn_exp2f(s[g][ct][1]);
                const float p2 = __builtin_amdgcn_exp2f(s[g][ct][2]);
                const float p3 = __builtin_amdgcn_exp2f(s[g][ct][3]);
                A[g][ct >> 1].u[(ct & 1) * 2 + 0] = pk2bf(p0, p1);
                A[g][ct >> 1].u[(ct & 1) * 2 + 1] = pk2bf(p2, p3);
            }
        }

        // ---- O += P V ; l += P . 1 — V-frags read ONCE, feed 4 q-groups ----
        __builtin_amdgcn_s_setprio(1);
        #pragma unroll
        for (int g = 0; g < 4; ++g) {
            acc_l[g] = __builtin_amdgcn_mfma_f32_16x16x32_bf16(A[g][0].v, ONES.v, acc_l[g], 0, 0, 0);
            acc_l[g] = __builtin_amdgcn_mfma_f32_16x16x32_bf16(A[g][1].v, ONES.v, acc_l[g], 0, 0, 0);
        }
        #pragma unroll
        for (int dt = 0; dt < 4; ++dt) {
            const bf16x8 v0 = *(const bf16x8*)&Vtile[vOff0[dt]];
            const bf16x8 v1 = *(const bf16x8*)&Vtile[vOff1[dt]];
            #pragma unroll
            for (int g = 0; g < 4; ++g) {
                o[g][dt] = __builtin_amdgcn_mfma_f32_16x16x32_bf16(A[g][0].v, v0, o[g][dt], 0, 0, 0);
                o[g][dt] = __builtin_amdgcn_mfma_f32_16x16x32_bf16(A[g][1].v, v1, o[g][dt], 0, 0, 0);
            }
        }
        __builtin_amdgcn_s_setprio(0);
    }

    // ---- epilogue: acc_l[g][i] is l for q-row row0+g*16+quad*4+i ----
    #pragma unroll
    for (int g = 0; g < 4; ++g) {
        #pragma unroll
        for (int i = 0; i < 4; ++i) {
            const float inv = 1.f / acc_l[g][i];
            const int r = row0 + g * 16 + quad * 4 + i;
            #pragma unroll
            for (int dt = 0; dt < 4; ++dt)
                ctx[qk_base + (size_t)r * H + dt * 16 + l15] = f2bf(o[g][dt][i] * inv);
        }
    }
}

// ---------------------------------------------------------------------------
// LayerNorm: one block per row of 1024, float4 loads.
// Wave shfl_xor reduction + single cross-wave LDS pass (1 barrier vs 8).
// ---------------------------------------------------------------------------
__global__ __launch_bounds__(256)
void ln_kernel(const float* __restrict__ Xr, const float* __restrict__ gamma,
               const float* __restrict__ beta, float* __restrict__ out)
{
    __shared__ float red[4], red2[4];
    const int row = blockIdx.x;
    const int tid = threadIdx.x;
    const int lane = tid & 63, w = tid >> 6;
    const float4 v = ((const float4*)(Xr + (size_t)row * H))[tid];
    float s  = v.x + v.y + v.z + v.w;
    float ss = v.x * v.x + v.y * v.y + v.z * v.z + v.w * v.w;
    #pragma unroll
    for (int d = 1; d < 64; d <<= 1) {
        s  += __shfl_xor(s, d);
        ss += __shfl_xor(ss, d);
    }
    if (lane == 0) { red[w] = s; red2[w] = ss; }
    __syncthreads();
    s  = red[0]  + red[1]  + red[2]  + red[3];
    ss = red2[0] + red2[1] + red2[2] + red2[3];
    const float mean = s * (1.f / H);
    const float var  = ss * (1.f / H) - mean * mean;
    const float rstd = rsqrtf(var + EPS);
    const float4 g  = ((const float4*)gamma)[tid];
    const float4 be = ((const float4*)beta)[tid];
    float4 o;
    o.x = g.x * (v.x - mean) * rstd + be.x;
    o.y = g.y * (v.y - mean) * rstd + be.y;
    o.z = g.z * (v.z - mean) * rstd + be.z;
    o.w = g.w * (v.w - mean) * rstd + be.w;
    ((float4*)(out + (size_t)row * H))[tid] = o;
}

// ---------------------------------------------------------------------------
extern "C" void kernel_launch(void* const* d_in, const int* in_sizes, int n_in,
                              void* d_out, int out_size, void* d_ws, size_t ws_size,
                              hipStream_t stream)
{
    const float* x     = (const float*)d_in[0];
    const float* Wq    = (const float*)d_in[1];
    const float* bq    = (const float*)d_in[2];
    const float* Wk    = (const float*)d_in[3];
    const float* bk    = (const float*)d_in[4];
    const float* Wv    = (const float*)d_in[5];
    const float* bv    = (const float*)d_in[6];
    const float* Wo    = (const float*)d_in[7];
    const float* bo    = (const float*)d_in[8];
    const float* gamma = (const float*)d_in[9];
    const float* beta  = (const float*)d_in[10];

    char* ws = (char*)d_ws;
    ushort* xb  = (ushort*)(ws);                       // 16 MB
    ushort* Wqb = (ushort*)(ws + (size_t)(16 << 20));  // 2 MB each
    ushort* Wkb = (ushort*)(ws + (size_t)(18 << 20));
    ushort* Wvb = (ushort*)(ws + (size_t)(20 << 20));
    ushort* Wob = (ushort*)(ws + (size_t)(22 << 20));
    ushort* Qb  = (ushort*)(ws + (size_t)(24 << 20));  // 16 MB (= ctx alias)
    ushort* Kb  = (ushort*)(ws + (size_t)(40 << 20));  // 16 MB
    ushort* Vt  = (ushort*)(ws + (size_t)(56 << 20));  // 16 MB
    float*  Xr  = (float*) (ws + (size_t)(40 << 20));  // 32 MB, aliases Kb+Vt (dead post-attn)

    cvt_all<<<12288, 256, 0, stream>>>((const float4*)x, (const float4*)Wq, (const float4*)Wk,
                                       (const float4*)Wv, (const float4*)Wo,
                                       (ushort4*)xb, (ushort4*)Wqb, (ushort4*)Wkb,
                                       (ushort4*)Wvb, (ushort4*)Wob);

    qkv_gemm<<<1536, 256, 0, stream>>>(
        xb, Wqb, Wkb, Wvb, bq, bk, bv, Qb, Kb, Vt);

    flash_attn_mfma<<<BB * NH * (SS / 256), 256, 0, stream>>>(Qb, Kb, Vt, Qb /*ctx*/);

    oproj_gemm<<<512, 256, 0, stream>>>(Qb, Wob, bo, x, Xr);

    ln_kernel<<<M_ROWS, 256, 0, stream>>>(Xr, gamma, beta, (float*)d_out);
}

// Round 10
// 267.669 us; speedup vs baseline: 1.2513x; 1.2513x over previous
//
#include <hip/hip_runtime.h>
#include <math.h>

#define H   1024
#define NH  16
#define DH  64
#define BB  4
#define SS  2048
#define M_ROWS (BB*SS)   // 8192
#define EPS 1e-12f
// 0.125 (=1/sqrt(DH)) * log2(e): scores come out in log2 domain -> raw v_exp_f32
#define QSCALE 0.18033688011112042f

typedef __attribute__((ext_vector_type(4))) float f32x4;
typedef __attribute__((ext_vector_type(8))) short bf16x8;
typedef const __attribute__((address_space(1))) void* as1cvp;
typedef __attribute__((address_space(3))) void*       as3vp;
typedef const __attribute__((address_space(1))) ushort* as1u;
typedef __attribute__((address_space(3))) ushort*       as3u;

__device__ __forceinline__ unsigned short f2bf(float f) {
    union { float f; unsigned u; } x; x.f = f;
    unsigned r = x.u + 0x7fffu + ((x.u >> 16) & 1u);   // RNE
    return (unsigned short)(r >> 16);
}
// pack two floats to packed bf16 (truncate) in ONE v_perm_b32
__device__ __forceinline__ unsigned pk2bf(float lo, float hi) {
    return __builtin_amdgcn_perm(__float_as_uint(hi), __float_as_uint(lo), 0x07060302u);
}

// ---------------------------------------------------------------------------
// Fused fp32 -> bf16 convert for x + all 4 weights. Grid exactly 12288 blocks.
// ---------------------------------------------------------------------------
__global__ __launch_bounds__(256)
void cvt_all(const float4* __restrict__ x,
             const float4* __restrict__ wq, const float4* __restrict__ wk,
             const float4* __restrict__ wv, const float4* __restrict__ wo,
             ushort4* __restrict__ xb, ushort4* __restrict__ wqb,
             ushort4* __restrict__ wkb, ushort4* __restrict__ wvb,
             ushort4* __restrict__ wob)
{
    int id = blockIdx.x * 256 + threadIdx.x;
    const float4* src; ushort4* dst; int off;
    if (id < 2097152) { src = x; dst = xb; off = id; }
    else {
        int t = id - 2097152, wsel = t >> 18;
        off = t & 262143;
        src = wsel == 0 ? wq : wsel == 1 ? wk : wsel == 2 ? wv : wo;
        dst = wsel == 0 ? wqb : wsel == 1 ? wkb : wsel == 2 ? wvb : wob;
    }
    float4 v = src[off];
    ushort4 o; o.x = f2bf(v.x); o.y = f2bf(v.y); o.z = f2bf(v.z); o.w = f2bf(v.w);
    dst[off] = o;
}

// ---------------------------------------------------------------------------
// GEMM core v6: 128x256 tile, 8 waves (512 thr), BK=64, THREE 48 KB LDS
// buffers, counted vmcnt(6) at a raw s_barrier (R8's proven pipeline).
// R9 falsified B-direct (scattered L2 requests, 68->121 us) -> ALL staging
// back through global_load_lds. R8/R7 arithmetic: a 128^2 tile needs
// 63 B/cyc/CU from L2 at full MFMA rate vs ~56 achievable -> structurally
// capped ~900 TF. 128x256 (85 FLOP/L2-byte) needs 46 B/cyc -> under the wall,
// and barriers drop 4x per FLOP (1 per BK=64 vs per BK=32 at half the tile).
// Staging per K-tile: A 128x64 (2 loads/thr-wave) + B 256x64 (4) = 6
// gload_lds per wave, issued contiguously. Steady state = 12 in flight;
// vmcnt(6) releases when tile n's 6 land, tile n+1's stay flying.
// WAR: buffer (n+2)%3 last read at iter n-1; all waves passed barrier n
// after their lgkmcnt-guarded MFMA reads -> safe (same proof as R8).
// LDS layout per buffer (ushort offsets): A half h at h*4096 + row*32,
// B half h at 8192 + h*8192 + row*32; chunk-swizzle c^=((row>>1)&3) via
// pre-swizzled global source (stage) / qsw (read) — identical to R8.
// ---------------------------------------------------------------------------
#define GL(gsrc, ldst) __builtin_amdgcn_global_load_lds((as1cvp)(gsrc), (as3vp)(ldst), 16, 0, 0)
#define STAGE_T(ofs, kt)                                                        \
    GL(gA + aOff  + (kt) * 64,      lds + (ofs) + w512);                        \
    GL(gA + aOff  + (kt) * 64 + 32, lds + (ofs) + 4096 + w512);                 \
    GL(gB + bOff0 + (kt) * 64,      lds + (ofs) + 8192 + w1024);                \
    GL(gB + bOff0 + (kt) * 64 + 32, lds + (ofs) + 16384 + w1024);               \
    GL(gB + bOff1 + (kt) * 64,      lds + (ofs) + 8192 + w1024 + 512);          \
    GL(gB + bOff1 + (kt) * 64 + 32, lds + (ofs) + 16384 + w1024 + 512);

__device__ __forceinline__ void gemm_core_256(const ushort* __restrict__ A,
                                              const ushort* __restrict__ Wt,
                                              ushort* ldsP,
                                              int row0, int col0, int K,
                                              f32x4 (&acc)[4][4])
{
    const int tid = threadIdx.x, lane = tid & 63, w = tid >> 6;   // w: 0..7
    const int wr = w >> 2, wc = w & 3, l15 = lane & 15, quad = lane >> 4;
    const int qsw = (quad ^ ((l15 >> 1) & 3)) * 8;  // fragment-read swizzle

    // staging: lane l covers row +(l>>2), chunk l&3; source chunk pre-swizzled
    const int sc = (lane & 3) ^ ((lane >> 3) & 3);

    const as1u gA = (as1u)A;
    const as1u gB = (as1u)Wt;
    as3u lds = (as3u)ldsP;

    const size_t aOff  = (size_t)(row0 + w * 16 + (lane >> 2)) * K + sc * 8;
    const size_t bOff0 = (size_t)(col0 + w * 32 + (lane >> 2)) * K + sc * 8;
    const size_t bOff1 = (size_t)(col0 + w * 32 + 16 + (lane >> 2)) * K + sc * 8;
    const int w512 = w * 512, w1024 = w * 1024;    // wave-uniform LDS bases

    const int NT = K >> 6;            // 16 K-tiles
    // prologue: tiles 0 and 1 in flight (12 loads outstanding)
    STAGE_T(0, 0);
    STAGE_T(24576, 1);

    int cur = 0;   // ushort offset of current buffer: 0 / 24576 / 49152
    for (int t = 0; t < NT; ++t) {
        if (t + 1 < NT) asm volatile("s_waitcnt vmcnt(6)" ::: "memory");
        else            asm volatile("s_waitcnt vmcnt(0)" ::: "memory");
        __builtin_amdgcn_s_barrier();

        int nxt2 = cur + 49152; if (nxt2 >= 73728) nxt2 -= 73728;  // (cur+2)%3
        if (t + 2 < NT) { STAGE_T(nxt2, t + 2); }

        const ushort* base = ldsP + cur;
        #pragma unroll
        for (int h = 0; h < 2; ++h) {
            const ushort* Ah = base + h * 4096;
            const ushort* Bh = base + 8192 + h * 8192;
            bf16x8 af[4], bfr[4];
            #pragma unroll
            for (int rt = 0; rt < 4; ++rt)
                af[rt] = *(const bf16x8*)&Ah[(wr * 64 + rt * 16 + l15) * 32 + qsw];
            #pragma unroll
            for (int ct = 0; ct < 4; ++ct)
                bfr[ct] = *(const bf16x8*)&Bh[(wc * 64 + ct * 16 + l15) * 32 + qsw];
            #pragma unroll
            for (int rt = 0; rt < 4; ++rt)
                #pragma unroll
                for (int ct = 0; ct < 4; ++ct)
                    acc[rt][ct] = __builtin_amdgcn_mfma_f32_16x16x32_bf16(af[rt], bfr[ct], acc[rt][ct], 0, 0, 0);
        }
        cur += 24576; if (cur == 73728) cur = 0;
    }
}

// ---------------------------------------------------------------------------
// Fused QKV projection: 768 blocks x 512 threads, tile 128x256.
// Grid = 3 slices x 64 rowtiles x 4 coltiles = 768 = exactly 3 rounds of
// 256 CUs at 1 block/CU (144 KB LDS) -> perfectly balanced.
// XCD swizzle (T1, verified R7): swz=(lin%8)*96+lin/8.
// ---------------------------------------------------------------------------
__global__ __launch_bounds__(512, 2)
void qkv_gemm(const ushort* __restrict__ xb,
              const ushort* __restrict__ Wqb, const ushort* __restrict__ Wkb,
              const ushort* __restrict__ Wvb,
              const float* __restrict__ bq, const float* __restrict__ bk,
              const float* __restrict__ bv,
              ushort* __restrict__ Qb, ushort* __restrict__ Kb, ushort* __restrict__ Vt)
{
    __shared__ __align__(16) ushort Ls[3 * 24576];  // 144 KB, 3 buffers
    const int lin = blockIdx.x;                     // 0..767
    const int swz = (lin & 7) * 96 + (lin >> 3);    // XCD-contiguous logical id
    const int z   = swz >> 8;                       // 0..2
    const int rem = swz & 255;
    const int row0 = (rem >> 2) * 128;
    const int col0 = (rem & 3) * 256;

    const ushort* Wt  = z == 0 ? Wqb : z == 1 ? Wkb : Wvb;
    const float* bias = z == 0 ? bq  : z == 1 ? bk  : bv;

    f32x4 acc[4][4];
    #pragma unroll
    for (int i = 0; i < 4; ++i)
        #pragma unroll
        for (int j = 0; j < 4; ++j)
            acc[i][j] = (f32x4){0.f, 0.f, 0.f, 0.f};

    gemm_core_256(xb, Wt, Ls, row0, col0, H, acc);

    const int tid = threadIdx.x, lane = tid & 63, w = tid >> 6;
    const int wr = w >> 2, wc = w & 3, l15 = lane & 15, quad = lane >> 4;

    #pragma unroll
    for (int rt = 0; rt < 4; ++rt) {
        const int r0g = row0 + wr * 64 + rt * 16 + quad * 4;
        #pragma unroll
        for (int ct = 0; ct < 4; ++ct) {
            const int c = col0 + wc * 64 + ct * 16 + l15;
            const float bs = bias[c];
            if (z == 0) {
                #pragma unroll
                for (int i = 0; i < 4; ++i)
                    Qb[(size_t)(r0g + i) * H + c] = f2bf((acc[rt][ct][i] + bs) * QSCALE);
            } else if (z == 1) {
                #pragma unroll
                for (int i = 0; i < 4; ++i)
                    Kb[(size_t)(r0g + i) * H + c] = f2bf(acc[rt][ct][i] + bs);
            } else {
                const int bb = r0g >> 11, s0 = r0g & 2047;
                const int hh = c >> 6, dd = c & 63;
                ushort4 o;
                o.x = f2bf(acc[rt][ct][0] + bs);
                o.y = f2bf(acc[rt][ct][1] + bs);
                o.z = f2bf(acc[rt][ct][2] + bs);
                o.w = f2bf(acc[rt][ct][3] + bs);
                *(ushort4*)&Vt[(((size_t)(bb * 16 + hh) * 64 + dd) << 11) + s0] = o;
            }
        }
    }
}

// ---------------------------------------------------------------------------
// O projection: fp32 out + residual. 256 blocks x 512 threads (1 round),
// tile 128x256; XCD swizzle swz=(lin%8)*32+lin/8.
// ---------------------------------------------------------------------------
__global__ __launch_bounds__(512, 2)
void oproj_gemm(const ushort* __restrict__ ctxb, const ushort* __restrict__ Wob,
                const float* __restrict__ bo, const float* __restrict__ res,
                float* __restrict__ Xr)
{
    __shared__ __align__(16) ushort Ls[3 * 24576];  // 144 KB, 3 buffers
    const int lin = blockIdx.x;                     // 0..255
    const int swz = (lin & 7) * 32 + (lin >> 3);
    const int row0 = (swz >> 2) * 128;
    const int col0 = (swz & 3) * 256;

    f32x4 acc[4][4];
    #pragma unroll
    for (int i = 0; i < 4; ++i)
        #pragma unroll
        for (int j = 0; j < 4; ++j)
            acc[i][j] = (f32x4){0.f, 0.f, 0.f, 0.f};

    gemm_core_256(ctxb, Wob, Ls, row0, col0, H, acc);

    const int tid = threadIdx.x, lane = tid & 63, w = tid >> 6;
    const int wr = w >> 2, wc = w & 3, l15 = lane & 15, quad = lane >> 4;

    #pragma unroll
    for (int rt = 0; rt < 4; ++rt) {
        const int r0g = row0 + wr * 64 + rt * 16 + quad * 4;
        #pragma unroll
        for (int ct = 0; ct < 4; ++ct) {
            const int c = col0 + wc * 64 + ct * 16 + l15;
            const float bs = bo[c];
            #pragma unroll
            for (int i = 0; i < 4; ++i) {
                size_t idx = (size_t)(r0g + i) * H + c;
                Xr[idx] = acc[rt][ct][i] + bs + res[idx];
            }
        }
    }
}

// ---------------------------------------------------------------------------
// Flash attention v6 (unchanged from R8): QBLK=64 per wave (4 q-groups),
// in-register P via permuted-K QK^T, l via ones-MFMA, one barrier/iter
// double-buffered K/V tiles. Near combined-issue saturation (~85%).
// ---------------------------------------------------------------------------
#define KTILE 64
#define NKT (SS / KTILE)   // 32

__global__ __launch_bounds__(256, 2)
void flash_attn_mfma(const ushort* __restrict__ Qb, const ushort* __restrict__ Kb,
                     const ushort* __restrict__ Vt, ushort* __restrict__ ctx)
{
    __shared__ __align__(16) ushort Ks[2][KTILE * 64];   // 2 x 8 KB
    __shared__ __align__(16) ushort Vs[2][64 * KTILE];   // 2 x 8 KB

    const int tid  = threadIdx.x;
    const int lane = tid & 63;
    const int w    = tid >> 6;
    const int l15  = lane & 15, quad = lane >> 4;
    const int bh   = blockIdx.x & 63;     // low bits -> same XCD per head
    const int qt   = blockIdx.x >> 6;     // 0..7 (256 q-rows per block)
    const int b    = bh >> 4, h = bh & 15;
    const int row0 = qt * 256 + w * 64;   // wave's 64 q-rows
    const size_t qk_base = (size_t)(b * SS) * H + h * DH;
    const size_t vt_base = (size_t)((b * 16 + h) * 64) * SS;

    const as1u gK = (const as1u)Kb;
    const as1u gV = (const as1u)Vt;

    // ---- staging lane constants: 8 rows x 8 chunks per gload_lds instr ----
    const int srow = lane >> 3;            // 0..7
    const int c8   = lane & 7;
    // f(row) = (row&3) | (((row>>3)&1)<<2); row = w*16 + t*8 + srow
    const int sck0 = c8 ^ ((srow & 3) | (((w * 2 + 0) & 1) << 2));  // t=0
    const int sck1 = c8 ^ ((srow & 3) | (((w * 2 + 1) & 1) << 2));  // t=1

    // ---- fragment-read lane constants (loop-invariant LDS ushort offsets) ----
    const int fL = (l15 & 3) | (((l15 >> 2) & 1) << 2);   // f(r) for K rows
    const int fV = (l15 & 3) | (((l15 >> 3) & 1) << 2);   // f(rv) for V rows
    const int rA = 8 * (l15 >> 2) + (l15 & 3);            // base K row (ct=0)
    int kOff0[4], kOff1[4], vOff0[4], vOff1[4];
    #pragma unroll
    for (int ct = 0; ct < 4; ++ct) {
        const int r = rA + (ct & 1) * 4 + (ct >> 1) * 32;
        kOff0[ct] = r * 64 + ((quad ^ fL) * 8);
        kOff1[ct] = r * 64 + (((4 | quad) ^ fL) * 8);
    }
    #pragma unroll
    for (int dt = 0; dt < 4; ++dt) {
        const int rv = dt * 16 + l15;
        vOff0[dt] = rv * 64 + ((quad ^ fV) * 8);
        vOff1[dt] = rv * 64 + (((4 | quad) ^ fV) * 8);
    }

    // Q fragments for all four q-groups
    bf16x8 aq[4][2];
    #pragma unroll
    for (int g = 0; g < 4; ++g) {
        const size_t qrow = qk_base + (size_t)(row0 + g * 16 + l15) * H;
        aq[g][0] = *(const bf16x8*)&Qb[qrow + quad * 8];
        aq[g][1] = *(const bf16x8*)&Qb[qrow + 32 + quad * 8];
    }

    // all-ones bf16 B-operand for the l rowsum MFMAs
    union { unsigned u[4]; bf16x8 v; } ONES;
    #pragma unroll
    for (int i = 0; i < 4; ++i) ONES.u[i] = 0x3F803F80u;

    f32x4 acc_l[4];
    f32x4 o[4][4];
    #pragma unroll
    for (int g = 0; g < 4; ++g) {
        acc_l[g] = (f32x4){0.f, 0.f, 0.f, 0.f};
        #pragma unroll
        for (int dt = 0; dt < 4; ++dt) o[g][dt] = (f32x4){0.f, 0.f, 0.f, 0.f};
    }

    // hoisted staging base pointers (row = w*16 + srow baked in)
    const as1u gK0 = gK + qk_base + (size_t)(w * 16 + srow) * H;
    const as1u gV0 = gV + vt_base + (size_t)(w * 16 + srow) * SS;

    // ---- stage tile 0 into buffer 0 ----
    __builtin_amdgcn_global_load_lds((as1cvp)(gK0 + sck0 * 8),
                                     (as3vp)(&Ks[0][(w * 16) * 64]), 16, 0, 0);
    __builtin_amdgcn_global_load_lds((as1cvp)(gK0 + (size_t)8 * H + sck1 * 8),
                                     (as3vp)(&Ks[0][(w * 16 + 8) * 64]), 16, 0, 0);
    __builtin_amdgcn_global_load_lds((as1cvp)(gV0 + sck0 * 8),
                                     (as3vp)(&Vs[0][(w * 16) * 64]), 16, 0, 0);
    __builtin_amdgcn_global_load_lds((as1cvp)(gV0 + (size_t)8 * SS + sck1 * 8),
                                     (as3vp)(&Vs[0][(w * 16 + 8) * 64]), 16, 0, 0);

    for (int kt = 0; kt < NKT; ++kt) {
        __syncthreads();   // tile kt landed (issued a full iter ago); prev reads done

        if (kt + 1 < NKT) {
            const int j0 = (kt + 1) * KTILE;
            const int nb = (kt + 1) & 1;
            __builtin_amdgcn_global_load_lds((as1cvp)(gK0 + (size_t)j0 * H + sck0 * 8),
                                             (as3vp)(&Ks[nb][(w * 16) * 64]), 16, 0, 0);
            __builtin_amdgcn_global_load_lds((as1cvp)(gK0 + (size_t)(j0 + 8) * H + sck1 * 8),
                                             (as3vp)(&Ks[nb][(w * 16 + 8) * 64]), 16, 0, 0);
            __builtin_amdgcn_global_load_lds((as1cvp)(gV0 + j0 + sck0 * 8),
                                             (as3vp)(&Vs[nb][(w * 16) * 64]), 16, 0, 0);
            __builtin_amdgcn_global_load_lds((as1cvp)(gV0 + (size_t)8 * SS + j0 + sck1 * 8),
                                             (as3vp)(&Vs[nb][(w * 16 + 8) * 64]), 16, 0, 0);
        }

        const ushort* Ktile = Ks[kt & 1];
        const ushort* Vtile = Vs[kt & 1];

        // ---- QK^T (permuted K rows): K-frags read ONCE, feed 4 q-groups ----
        f32x4 s[4][4];
        __builtin_amdgcn_s_setprio(1);
        #pragma unroll
        for (int ct = 0; ct < 4; ++ct) {
            const bf16x8 k0 = *(const bf16x8*)&Ktile[kOff0[ct]];
            const bf16x8 k1 = *(const bf16x8*)&Ktile[kOff1[ct]];
            #pragma unroll
            for (int g = 0; g < 4; ++g) {
                f32x4 z = (f32x4){0.f, 0.f, 0.f, 0.f};
                z = __builtin_amdgcn_mfma_f32_16x16x32_bf16(k0, aq[g][0], z, 0, 0, 0);
                z = __builtin_amdgcn_mfma_f32_16x16x32_bf16(k1, aq[g][1], z, 0, 0, 0);
                s[g][ct] = z;
            }
        }
        __builtin_amdgcn_s_setprio(0);

        // ---- exp2 + v_perm pack per group: registers become PV A-fragments ----
        union { unsigned u[4]; bf16x8 v; } A[4][2];
        #pragma unroll
        for (int g = 0; g < 4; ++g) {
            #pragma unroll
            for (int ct = 0; ct < 4; ++ct) {
                const float p0 = __builtin_amdgcn_exp2f(s[g][ct][0]);
                const float p1 = __builtin_amdgcn_exp2f(s[g][ct][1]);
                const float p2 = __builtin_amdgcn_exp2f(s[g][ct][2]);
                const float p3 = __builtin_amdgcn_exp2f(s[g][ct][3]);
                A[g][ct >> 1].u[(ct & 1) * 2 + 0] = pk2bf(p0, p1);
                A[g][ct >> 1].u[(ct & 1) * 2 + 1] = pk2bf(p2, p3);
            }
        }

        // ---- O += P V ; l += P . 1 — V-frags read ONCE, feed 4 q-groups ----
        __builtin_amdgcn_s_setprio(1);
        #pragma unroll
        for (int g = 0; g < 4; ++g) {
            acc_l[g] = __builtin_amdgcn_mfma_f32_16x16x32_bf16(A[g][0].v, ONES.v, acc_l[g], 0, 0, 0);
            acc_l[g] = __builtin_amdgcn_mfma_f32_16x16x32_bf16(A[g][1].v, ONES.v, acc_l[g], 0, 0, 0);
        }
        #pragma unroll
        for (int dt = 0; dt < 4; ++dt) {
            const bf16x8 v0 = *(const bf16x8*)&Vtile[vOff0[dt]];
            const bf16x8 v1 = *(const bf16x8*)&Vtile[vOff1[dt]];
            #pragma unroll
            for (int g = 0; g < 4; ++g) {
                o[g][dt] = __builtin_amdgcn_mfma_f32_16x16x32_bf16(A[g][0].v, v0, o[g][dt], 0, 0, 0);
                o[g][dt] = __builtin_amdgcn_mfma_f32_16x16x32_bf16(A[g][1].v, v1, o[g][dt], 0, 0, 0);
            }
        }
        __builtin_amdgcn_s_setprio(0);
    }

    // ---- epilogue: acc_l[g][i] is l for q-row row0+g*16+quad*4+i ----
    #pragma unroll
    for (int g = 0; g < 4; ++g) {
        #pragma unroll
        for (int i = 0; i < 4; ++i) {
            const float inv = 1.f / acc_l[g][i];
            const int r = row0 + g * 16 + quad * 4 + i;
            #pragma unroll
            for (int dt = 0; dt < 4; ++dt)
                ctx[qk_base + (size_t)r * H + dt * 16 + l15] = f2bf(o[g][dt][i] * inv);
        }
    }
}

// ---------------------------------------------------------------------------
// LayerNorm: one block per row of 1024, float4 loads.
// Wave shfl_xor reduction + single cross-wave LDS pass (1 barrier vs 8).
// ---------------------------------------------------------------------------
__global__ __launch_bounds__(256)
void ln_kernel(const float* __restrict__ Xr, const float* __restrict__ gamma,
               const float* __restrict__ beta, float* __restrict__ out)
{
    __shared__ float red[4], red2[4];
    const int row = blockIdx.x;
    const int tid = threadIdx.x;
    const int lane = tid & 63, w = tid >> 6;
    const float4 v = ((const float4*)(Xr + (size_t)row * H))[tid];
    float s  = v.x + v.y + v.z + v.w;
    float ss = v.x * v.x + v.y * v.y + v.z * v.z + v.w * v.w;
    #pragma unroll
    for (int d = 1; d < 64; d <<= 1) {
        s  += __shfl_xor(s, d);
        ss += __shfl_xor(ss, d);
    }
    if (lane == 0) { red[w] = s; red2[w] = ss; }
    __syncthreads();
    s  = red[0]  + red[1]  + red[2]  + red[3];
    ss = red2[0] + red2[1] + red2[2] + red2[3];
    const float mean = s * (1.f / H);
    const float var  = ss * (1.f / H) - mean * mean;
    const float rstd = rsqrtf(var + EPS);
    const float4 g  = ((const float4*)gamma)[tid];
    const float4 be = ((const float4*)beta)[tid];
    float4 o;
    o.x = g.x * (v.x - mean) * rstd + be.x;
    o.y = g.y * (v.y - mean) * rstd + be.y;
    o.z = g.z * (v.z - mean) * rstd + be.z;
    o.w = g.w * (v.w - mean) * rstd + be.w;
    ((float4*)(out + (size_t)row * H))[tid] = o;
}

// ---------------------------------------------------------------------------
extern "C" void kernel_launch(void* const* d_in, const int* in_sizes, int n_in,
                              void* d_out, int out_size, void* d_ws, size_t ws_size,
                              hipStream_t stream)
{
    const float* x     = (const float*)d_in[0];
    const float* Wq    = (const float*)d_in[1];
    const float* bq    = (const float*)d_in[2];
    const float* Wk    = (const float*)d_in[3];
    const float* bk    = (const float*)d_in[4];
    const float* Wv    = (const float*)d_in[5];
    const float* bv    = (const float*)d_in[6];
    const float* Wo    = (const float*)d_in[7];
    const float* bo    = (const float*)d_in[8];
    const float* gamma = (const float*)d_in[9];
    const float* beta  = (const float*)d_in[10];

    char* ws = (char*)d_ws;
    ushort* xb  = (ushort*)(ws);                       // 16 MB
    ushort* Wqb = (ushort*)(ws + (size_t)(16 << 20));  // 2 MB each
    ushort* Wkb = (ushort*)(ws + (size_t)(18 << 20));
    ushort* Wvb = (ushort*)(ws + (size_t)(20 << 20));
    ushort* Wob = (ushort*)(ws + (size_t)(22 << 20));
    ushort* Qb  = (ushort*)(ws + (size_t)(24 << 20));  // 16 MB (= ctx alias)
    ushort* Kb  = (ushort*)(ws + (size_t)(40 << 20));  // 16 MB
    ushort* Vt  = (ushort*)(ws + (size_t)(56 << 20));  // 16 MB
    float*  Xr  = (float*) (ws + (size_t)(40 << 20));  // 32 MB, aliases Kb+Vt (dead post-attn)

    cvt_all<<<12288, 256, 0, stream>>>((const float4*)x, (const float4*)Wq, (const float4*)Wk,
                                       (const float4*)Wv, (const float4*)Wo,
                                       (ushort4*)xb, (ushort4*)Wqb, (ushort4*)Wkb,
                                       (ushort4*)Wvb, (ushort4*)Wob);

    qkv_gemm<<<768, 512, 0, stream>>>(
        xb, Wqb, Wkb, Wvb, bq, bk, bv, Qb, Kb, Vt);

    flash_attn_mfma<<<BB * NH * (SS / 256), 256, 0, stream>>>(Qb, Kb, Vt, Qb /*ctx*/);

    oproj_gemm<<<256, 512, 0, stream>>>(Qb, Wob, bo, x, Xr);

    ln_kernel<<<M_ROWS, 256, 0, stream>>>(Xr, gamma, beta, (float*)d_out);
}

// Round 11
// 265.663 us; speedup vs baseline: 1.2607x; 1.0076x over previous
//
#include <hip/hip_runtime.h>
#include <math.h>

#define H   1024
#define NH  16
#define DH  64
#define BB  4
#define SS  2048
#define M_ROWS (BB*SS)   // 8192
#define EPS 1e-12f
// 0.125 (=1/sqrt(DH)) * log2(e): scores come out in log2 domain -> raw v_exp_f32
#define QSCALE 0.18033688011112042f

typedef __attribute__((ext_vector_type(4))) float f32x4;
typedef __attribute__((ext_vector_type(8))) short bf16x8;
typedef const __attribute__((address_space(1))) void* as1cvp;
typedef __attribute__((address_space(3))) void*       as3vp;
typedef const __attribute__((address_space(1))) ushort* as1u;
typedef __attribute__((address_space(3))) ushort*       as3u;

__device__ __forceinline__ unsigned short f2bf(float f) {
    union { float f; unsigned u; } x; x.f = f;
    unsigned r = x.u + 0x7fffu + ((x.u >> 16) & 1u);   // RNE
    return (unsigned short)(r >> 16);
}
// pack two floats to packed bf16 (truncate) in ONE v_perm_b32
__device__ __forceinline__ unsigned pk2bf(float lo, float hi) {
    return __builtin_amdgcn_perm(__float_as_uint(hi), __float_as_uint(lo), 0x07060302u);
}

// ---------------------------------------------------------------------------
// Fused fp32 -> bf16 convert for x + all 4 weights. Grid exactly 12288 blocks.
// ---------------------------------------------------------------------------
__global__ __launch_bounds__(256)
void cvt_all(const float4* __restrict__ x,
             const float4* __restrict__ wq, const float4* __restrict__ wk,
             const float4* __restrict__ wv, const float4* __restrict__ wo,
             ushort4* __restrict__ xb, ushort4* __restrict__ wqb,
             ushort4* __restrict__ wkb, ushort4* __restrict__ wvb,
             ushort4* __restrict__ wob)
{
    int id = blockIdx.x * 256 + threadIdx.x;
    const float4* src; ushort4* dst; int off;
    if (id < 2097152) { src = x; dst = xb; off = id; }
    else {
        int t = id - 2097152, wsel = t >> 18;
        off = t & 262143;
        src = wsel == 0 ? wq : wsel == 1 ? wk : wsel == 2 ? wv : wo;
        dst = wsel == 0 ? wqb : wsel == 1 ? wkb : wsel == 2 ? wvb : wob;
    }
    float4 v = src[off];
    ushort4 o; o.x = f2bf(v.x); o.y = f2bf(v.y); o.z = f2bf(v.z); o.w = f2bf(v.w);
    dst[off] = o;
}

// ---------------------------------------------------------------------------
// GEMM core v6 (unchanged from R10): 128x256 tile, 8 waves, BK=64, three
// 48 KB LDS buffers, counted vmcnt(6) at a raw s_barrier.
// ---------------------------------------------------------------------------
#define GL(gsrc, ldst) __builtin_amdgcn_global_load_lds((as1cvp)(gsrc), (as3vp)(ldst), 16, 0, 0)
#define STAGE_T(ofs, kt)                                                        \
    GL(gA + aOff  + (kt) * 64,      lds + (ofs) + w512);                        \
    GL(gA + aOff  + (kt) * 64 + 32, lds + (ofs) + 4096 + w512);                 \
    GL(gB + bOff0 + (kt) * 64,      lds + (ofs) + 8192 + w1024);                \
    GL(gB + bOff0 + (kt) * 64 + 32, lds + (ofs) + 16384 + w1024);               \
    GL(gB + bOff1 + (kt) * 64,      lds + (ofs) + 8192 + w1024 + 512);          \
    GL(gB + bOff1 + (kt) * 64 + 32, lds + (ofs) + 16384 + w1024 + 512);

__device__ __forceinline__ void gemm_core_256(const ushort* __restrict__ A,
                                              const ushort* __restrict__ Wt,
                                              ushort* ldsP,
                                              int row0, int col0, int K,
                                              f32x4 (&acc)[4][4])
{
    const int tid = threadIdx.x, lane = tid & 63, w = tid >> 6;   // w: 0..7
    const int wr = w >> 2, wc = w & 3, l15 = lane & 15, quad = lane >> 4;
    const int qsw = (quad ^ ((l15 >> 1) & 3)) * 8;  // fragment-read swizzle

    // staging: lane l covers row +(l>>2), chunk l&3; source chunk pre-swizzled
    const int sc = (lane & 3) ^ ((lane >> 3) & 3);

    const as1u gA = (as1u)A;
    const as1u gB = (as1u)Wt;
    as3u lds = (as3u)ldsP;

    const size_t aOff  = (size_t)(row0 + w * 16 + (lane >> 2)) * K + sc * 8;
    const size_t bOff0 = (size_t)(col0 + w * 32 + (lane >> 2)) * K + sc * 8;
    const size_t bOff1 = (size_t)(col0 + w * 32 + 16 + (lane >> 2)) * K + sc * 8;
    const int w512 = w * 512, w1024 = w * 1024;    // wave-uniform LDS bases

    const int NT = K >> 6;            // 16 K-tiles
    // prologue: tiles 0 and 1 in flight (12 loads outstanding)
    STAGE_T(0, 0);
    STAGE_T(24576, 1);

    int cur = 0;   // ushort offset of current buffer: 0 / 24576 / 49152
    for (int t = 0; t < NT; ++t) {
        if (t + 1 < NT) asm volatile("s_waitcnt vmcnt(6)" ::: "memory");
        else            asm volatile("s_waitcnt vmcnt(0)" ::: "memory");
        __builtin_amdgcn_s_barrier();

        int nxt2 = cur + 49152; if (nxt2 >= 73728) nxt2 -= 73728;  // (cur+2)%3
        if (t + 2 < NT) { STAGE_T(nxt2, t + 2); }

        const ushort* base = ldsP + cur;
        #pragma unroll
        for (int h = 0; h < 2; ++h) {
            const ushort* Ah = base + h * 4096;
            const ushort* Bh = base + 8192 + h * 8192;
            bf16x8 af[4], bfr[4];
            #pragma unroll
            for (int rt = 0; rt < 4; ++rt)
                af[rt] = *(const bf16x8*)&Ah[(wr * 64 + rt * 16 + l15) * 32 + qsw];
            #pragma unroll
            for (int ct = 0; ct < 4; ++ct)
                bfr[ct] = *(const bf16x8*)&Bh[(wc * 64 + ct * 16 + l15) * 32 + qsw];
            #pragma unroll
            for (int rt = 0; rt < 4; ++rt)
                #pragma unroll
                for (int ct = 0; ct < 4; ++ct)
                    acc[rt][ct] = __builtin_amdgcn_mfma_f32_16x16x32_bf16(af[rt], bfr[ct], acc[rt][ct], 0, 0, 0);
        }
        cur += 24576; if (cur == 73728) cur = 0;
    }
}

// ---------------------------------------------------------------------------
// Fused QKV projection: 768 blocks x 512 threads, tile 128x256.
// XCD swizzle (T1): swz=(lin%8)*96+lin/8.
// ---------------------------------------------------------------------------
__global__ __launch_bounds__(512, 2)
void qkv_gemm(const ushort* __restrict__ xb,
              const ushort* __restrict__ Wqb, const ushort* __restrict__ Wkb,
              const ushort* __restrict__ Wvb,
              const float* __restrict__ bq, const float* __restrict__ bk,
              const float* __restrict__ bv,
              ushort* __restrict__ Qb, ushort* __restrict__ Kb, ushort* __restrict__ Vt)
{
    __shared__ __align__(16) ushort Ls[3 * 24576];  // 144 KB, 3 buffers
    const int lin = blockIdx.x;                     // 0..767
    const int swz = (lin & 7) * 96 + (lin >> 3);    // XCD-contiguous logical id
    const int z   = swz >> 8;                       // 0..2
    const int rem = swz & 255;
    const int row0 = (rem >> 2) * 128;
    const int col0 = (rem & 3) * 256;

    const ushort* Wt  = z == 0 ? Wqb : z == 1 ? Wkb : Wvb;
    const float* bias = z == 0 ? bq  : z == 1 ? bk  : bv;

    f32x4 acc[4][4];
    #pragma unroll
    for (int i = 0; i < 4; ++i)
        #pragma unroll
        for (int j = 0; j < 4; ++j)
            acc[i][j] = (f32x4){0.f, 0.f, 0.f, 0.f};

    gemm_core_256(xb, Wt, Ls, row0, col0, H, acc);

    const int tid = threadIdx.x, lane = tid & 63, w = tid >> 6;
    const int wr = w >> 2, wc = w & 3, l15 = lane & 15, quad = lane >> 4;

    #pragma unroll
    for (int rt = 0; rt < 4; ++rt) {
        const int r0g = row0 + wr * 64 + rt * 16 + quad * 4;
        #pragma unroll
        for (int ct = 0; ct < 4; ++ct) {
            const int c = col0 + wc * 64 + ct * 16 + l15;
            const float bs = bias[c];
            if (z == 0) {
                #pragma unroll
                for (int i = 0; i < 4; ++i)
                    Qb[(size_t)(r0g + i) * H + c] = f2bf((acc[rt][ct][i] + bs) * QSCALE);
            } else if (z == 1) {
                #pragma unroll
                for (int i = 0; i < 4; ++i)
                    Kb[(size_t)(r0g + i) * H + c] = f2bf(acc[rt][ct][i] + bs);
            } else {
                const int bb = r0g >> 11, s0 = r0g & 2047;
                const int hh = c >> 6, dd = c & 63;
                ushort4 o;
                o.x = f2bf(acc[rt][ct][0] + bs);
                o.y = f2bf(acc[rt][ct][1] + bs);
                o.z = f2bf(acc[rt][ct][2] + bs);
                o.w = f2bf(acc[rt][ct][3] + bs);
                *(ushort4*)&Vt[(((size_t)(bb * 16 + hh) * 64 + dd) << 11) + s0] = o;
            }
        }
    }
}

// ---------------------------------------------------------------------------
// O projection: fp32 out + residual. 256 blocks x 512 threads, tile 128x256.
// ---------------------------------------------------------------------------
__global__ __launch_bounds__(512, 2)
void oproj_gemm(const ushort* __restrict__ ctxb, const ushort* __restrict__ Wob,
                const float* __restrict__ bo, const float* __restrict__ res,
                float* __restrict__ Xr)
{
    __shared__ __align__(16) ushort Ls[3 * 24576];  // 144 KB, 3 buffers
    const int lin = blockIdx.x;                     // 0..255
    const int swz = (lin & 7) * 32 + (lin >> 3);
    const int row0 = (swz >> 2) * 128;
    const int col0 = (swz & 3) * 256;

    f32x4 acc[4][4];
    #pragma unroll
    for (int i = 0; i < 4; ++i)
        #pragma unroll
        for (int j = 0; j < 4; ++j)
            acc[i][j] = (f32x4){0.f, 0.f, 0.f, 0.f};

    gemm_core_256(ctxb, Wob, Ls, row0, col0, H, acc);

    const int tid = threadIdx.x, lane = tid & 63, w = tid >> 6;
    const int wr = w >> 2, wc = w & 3, l15 = lane & 15, quad = lane >> 4;

    #pragma unroll
    for (int rt = 0; rt < 4; ++rt) {
        const int r0g = row0 + wr * 64 + rt * 16 + quad * 4;
        #pragma unroll
        for (int ct = 0; ct < 4; ++ct) {
            const int c = col0 + wc * 64 + ct * 16 + l15;
            const float bs = bo[c];
            #pragma unroll
            for (int i = 0; i < 4; ++i) {
                size_t idx = (size_t)(r0g + i) * H + c;
                Xr[idx] = acc[rt][ct][i] + bs + res[idx];
            }
        }
    }
}

// ---------------------------------------------------------------------------
// Flash attention v7: PHASE-STAGGERED pipeline across q-groups.
// R10 accounting: per iter per wave, MFMA pipe needs 1152 cyc and VALU needs
// ~1150 cyc — nearly perfectly balanced — yet both sat at ~43% because the
// three phases (QK -> exp -> PV) were serial per wave and barrier-locked
// across waves. v7 staggers: QK(g0); for g: {QK(g+1) || exp(g) -> PV(g)}.
// QK(g+1) MFMAs are independent of exp(g) VALU; PV(g) MFMAs are independent
// of exp(g+1) — the unrolled dep graph lets the scheduler co-issue both
// pipes from one instruction stream. All 16 K/V fragment ds_reads hoisted
// to the iteration top (lgkm waits overlap staging).
// VGPR ~236 (falsifier: >256 or scratch -> revert). Else same as v6.
// ---------------------------------------------------------------------------
#define KTILE 64
#define NKT (SS / KTILE)   // 32

__global__ __launch_bounds__(256, 2)
void flash_attn_mfma(const ushort* __restrict__ Qb, const ushort* __restrict__ Kb,
                     const ushort* __restrict__ Vt, ushort* __restrict__ ctx)
{
    __shared__ __align__(16) ushort Ks[2][KTILE * 64];   // 2 x 8 KB
    __shared__ __align__(16) ushort Vs[2][64 * KTILE];   // 2 x 8 KB

    const int tid  = threadIdx.x;
    const int lane = tid & 63;
    const int w    = tid >> 6;
    const int l15  = lane & 15, quad = lane >> 4;
    const int bh   = blockIdx.x & 63;     // low bits -> same XCD per head
    const int qt   = blockIdx.x >> 6;     // 0..7 (256 q-rows per block)
    const int b    = bh >> 4, h = bh & 15;
    const int row0 = qt * 256 + w * 64;   // wave's 64 q-rows
    const size_t qk_base = (size_t)(b * SS) * H + h * DH;
    const size_t vt_base = (size_t)((b * 16 + h) * 64) * SS;

    const as1u gK = (const as1u)Kb;
    const as1u gV = (const as1u)Vt;

    // ---- staging lane constants: 8 rows x 8 chunks per gload_lds instr ----
    const int srow = lane >> 3;            // 0..7
    const int c8   = lane & 7;
    // f(row) = (row&3) | (((row>>3)&1)<<2); row = w*16 + t*8 + srow
    const int sck0 = c8 ^ ((srow & 3) | (((w * 2 + 0) & 1) << 2));  // t=0
    const int sck1 = c8 ^ ((srow & 3) | (((w * 2 + 1) & 1) << 2));  // t=1

    // ---- fragment-read lane constants (loop-invariant LDS ushort offsets) ----
    const int fL = (l15 & 3) | (((l15 >> 2) & 1) << 2);   // f(r) for K rows
    const int fV = (l15 & 3) | (((l15 >> 3) & 1) << 2);   // f(rv) for V rows
    const int rA = 8 * (l15 >> 2) + (l15 & 3);            // base K row (ct=0)
    int kOff0[4], kOff1[4], vOff0[4], vOff1[4];
    #pragma unroll
    for (int ct = 0; ct < 4; ++ct) {
        const int r = rA + (ct & 1) * 4 + (ct >> 1) * 32;
        kOff0[ct] = r * 64 + ((quad ^ fL) * 8);
        kOff1[ct] = r * 64 + (((4 | quad) ^ fL) * 8);
    }
    #pragma unroll
    for (int dt = 0; dt < 4; ++dt) {
        const int rv = dt * 16 + l15;
        vOff0[dt] = rv * 64 + ((quad ^ fV) * 8);
        vOff1[dt] = rv * 64 + (((4 | quad) ^ fV) * 8);
    }

    // Q fragments for all four q-groups
    bf16x8 aq[4][2];
    #pragma unroll
    for (int g = 0; g < 4; ++g) {
        const size_t qrow = qk_base + (size_t)(row0 + g * 16 + l15) * H;
        aq[g][0] = *(const bf16x8*)&Qb[qrow + quad * 8];
        aq[g][1] = *(const bf16x8*)&Qb[qrow + 32 + quad * 8];
    }

    // all-ones bf16 B-operand for the l rowsum MFMAs
    union { unsigned u[4]; bf16x8 v; } ONES;
    #pragma unroll
    for (int i = 0; i < 4; ++i) ONES.u[i] = 0x3F803F80u;

    f32x4 acc_l[4];
    f32x4 o[4][4];
    #pragma unroll
    for (int g = 0; g < 4; ++g) {
        acc_l[g] = (f32x4){0.f, 0.f, 0.f, 0.f};
        #pragma unroll
        for (int dt = 0; dt < 4; ++dt) o[g][dt] = (f32x4){0.f, 0.f, 0.f, 0.f};
    }

    // hoisted staging base pointers (row = w*16 + srow baked in)
    const as1u gK0 = gK + qk_base + (size_t)(w * 16 + srow) * H;
    const as1u gV0 = gV + vt_base + (size_t)(w * 16 + srow) * SS;

    // ---- stage tile 0 into buffer 0 ----
    __builtin_amdgcn_global_load_lds((as1cvp)(gK0 + sck0 * 8),
                                     (as3vp)(&Ks[0][(w * 16) * 64]), 16, 0, 0);
    __builtin_amdgcn_global_load_lds((as1cvp)(gK0 + (size_t)8 * H + sck1 * 8),
                                     (as3vp)(&Ks[0][(w * 16 + 8) * 64]), 16, 0, 0);
    __builtin_amdgcn_global_load_lds((as1cvp)(gV0 + sck0 * 8),
                                     (as3vp)(&Vs[0][(w * 16) * 64]), 16, 0, 0);
    __builtin_amdgcn_global_load_lds((as1cvp)(gV0 + (size_t)8 * SS + sck1 * 8),
                                     (as3vp)(&Vs[0][(w * 16 + 8) * 64]), 16, 0, 0);

    for (int kt = 0; kt < NKT; ++kt) {
        __syncthreads();   // tile kt landed (issued a full iter ago); prev reads done

        if (kt + 1 < NKT) {
            const int j0 = (kt + 1) * KTILE;
            const int nb = (kt + 1) & 1;
            __builtin_amdgcn_global_load_lds((as1cvp)(gK0 + (size_t)j0 * H + sck0 * 8),
                                             (as3vp)(&Ks[nb][(w * 16) * 64]), 16, 0, 0);
            __builtin_amdgcn_global_load_lds((as1cvp)(gK0 + (size_t)(j0 + 8) * H + sck1 * 8),
                                             (as3vp)(&Ks[nb][(w * 16 + 8) * 64]), 16, 0, 0);
            __builtin_amdgcn_global_load_lds((as1cvp)(gV0 + j0 + sck0 * 8),
                                             (as3vp)(&Vs[nb][(w * 16) * 64]), 16, 0, 0);
            __builtin_amdgcn_global_load_lds((as1cvp)(gV0 + (size_t)8 * SS + j0 + sck1 * 8),
                                             (as3vp)(&Vs[nb][(w * 16 + 8) * 64]), 16, 0, 0);
        }

        const ushort* Ktile = Ks[kt & 1];
        const ushort* Vtile = Vs[kt & 1];

        // ---- hoist ALL K/V fragment reads (16 x ds_read_b128) ----
        bf16x8 kf0[4], kf1[4], vf0[4], vf1[4];
        #pragma unroll
        for (int ct = 0; ct < 4; ++ct) {
            kf0[ct] = *(const bf16x8*)&Ktile[kOff0[ct]];
            kf1[ct] = *(const bf16x8*)&Ktile[kOff1[ct]];
        }
        #pragma unroll
        for (int dt = 0; dt < 4; ++dt) {
            vf0[dt] = *(const bf16x8*)&Vtile[vOff0[dt]];
            vf1[dt] = *(const bf16x8*)&Vtile[vOff1[dt]];
        }

        f32x4 sg[4][4];
        __builtin_amdgcn_s_setprio(1);
        // ---- QK for group 0 ----
        #pragma unroll
        for (int ct = 0; ct < 4; ++ct) {
            f32x4 z = (f32x4){0.f, 0.f, 0.f, 0.f};
            z = __builtin_amdgcn_mfma_f32_16x16x32_bf16(kf0[ct], aq[0][0], z, 0, 0, 0);
            sg[0][ct] = __builtin_amdgcn_mfma_f32_16x16x32_bf16(kf1[ct], aq[0][1], z, 0, 0, 0);
        }
        // ---- staggered: QK(g+1) || exp(g) -> PV(g) ----
        #pragma unroll
        for (int g = 0; g < 4; ++g) {
            if (g + 1 < 4) {
                #pragma unroll
                for (int ct = 0; ct < 4; ++ct) {
                    f32x4 z = (f32x4){0.f, 0.f, 0.f, 0.f};
                    z = __builtin_amdgcn_mfma_f32_16x16x32_bf16(kf0[ct], aq[g + 1][0], z, 0, 0, 0);
                    sg[g + 1][ct] = __builtin_amdgcn_mfma_f32_16x16x32_bf16(kf1[ct], aq[g + 1][1], z, 0, 0, 0);
                }
            }
            union { unsigned u[4]; bf16x8 v; } A0, A1;
            #pragma unroll
            for (int ct = 0; ct < 4; ++ct) {
                const float p0 = __builtin_amdgcn_exp2f(sg[g][ct][0]);
                const float p1 = __builtin_amdgcn_exp2f(sg[g][ct][1]);
                const float p2 = __builtin_amdgcn_exp2f(sg[g][ct][2]);
                const float p3 = __builtin_amdgcn_exp2f(sg[g][ct][3]);
                if (ct < 2) {
                    A0.u[(ct & 1) * 2 + 0] = pk2bf(p0, p1);
                    A0.u[(ct & 1) * 2 + 1] = pk2bf(p2, p3);
                } else {
                    A1.u[(ct & 1) * 2 + 0] = pk2bf(p0, p1);
                    A1.u[(ct & 1) * 2 + 1] = pk2bf(p2, p3);
                }
            }
            acc_l[g] = __builtin_amdgcn_mfma_f32_16x16x32_bf16(A0.v, ONES.v, acc_l[g], 0, 0, 0);
            acc_l[g] = __builtin_amdgcn_mfma_f32_16x16x32_bf16(A1.v, ONES.v, acc_l[g], 0, 0, 0);
            #pragma unroll
            for (int dt = 0; dt < 4; ++dt) {
                o[g][dt] = __builtin_amdgcn_mfma_f32_16x16x32_bf16(A0.v, vf0[dt], o[g][dt], 0, 0, 0);
                o[g][dt] = __builtin_amdgcn_mfma_f32_16x16x32_bf16(A1.v, vf1[dt], o[g][dt], 0, 0, 0);
            }
        }
        __builtin_amdgcn_s_setprio(0);
    }

    // ---- epilogue: acc_l[g][i] is l for q-row row0+g*16+quad*4+i ----
    #pragma unroll
    for (int g = 0; g < 4; ++g) {
        #pragma unroll
        for (int i = 0; i < 4; ++i) {
            const float inv = 1.f / acc_l[g][i];
            const int r = row0 + g * 16 + quad * 4 + i;
            #pragma unroll
            for (int dt = 0; dt < 4; ++dt)
                ctx[qk_base + (size_t)r * H + dt * 16 + l15] = f2bf(o[g][dt][i] * inv);
        }
    }
}

// ---------------------------------------------------------------------------
// LayerNorm: one block per row of 1024, float4 loads.
// Wave shfl_xor reduction + single cross-wave LDS pass (1 barrier vs 8).
// ---------------------------------------------------------------------------
__global__ __launch_bounds__(256)
void ln_kernel(const float* __restrict__ Xr, const float* __restrict__ gamma,
               const float* __restrict__ beta, float* __restrict__ out)
{
    __shared__ float red[4], red2[4];
    const int row = blockIdx.x;
    const int tid = threadIdx.x;
    const int lane = tid & 63, w = tid >> 6;
    const float4 v = ((const float4*)(Xr + (size_t)row * H))[tid];
    float s  = v.x + v.y + v.z + v.w;
    float ss = v.x * v.x + v.y * v.y + v.z * v.z + v.w * v.w;
    #pragma unroll
    for (int d = 1; d < 64; d <<= 1) {
        s  += __shfl_xor(s, d);
        ss += __shfl_xor(ss, d);
    }
    if (lane == 0) { red[w] = s; red2[w] = ss; }
    __syncthreads();
    s  = red[0]  + red[1]  + red[2]  + red[3];
    ss = red2[0] + red2[1] + red2[2] + red2[3];
    const float mean = s * (1.f / H);
    const float var  = ss * (1.f / H) - mean * mean;
    const float rstd = rsqrtf(var + EPS);
    const float4 g  = ((const float4*)gamma)[tid];
    const float4 be = ((const float4*)beta)[tid];
    float4 o;
    o.x = g.x * (v.x - mean) * rstd + be.x;
    o.y = g.y * (v.y - mean) * rstd + be.y;
    o.z = g.z * (v.z - mean) * rstd + be.z;
    o.w = g.w * (v.w - mean) * rstd + be.w;
    ((float4*)(out + (size_t)row * H))[tid] = o;
}

// ---------------------------------------------------------------------------
extern "C" void kernel_launch(void* const* d_in, const int* in_sizes, int n_in,
                              void* d_out, int out_size, void* d_ws, size_t ws_size,
                              hipStream_t stream)
{
    const float* x     = (const float*)d_in[0];
    const float* Wq    = (const float*)d_in[1];
    const float* bq    = (const float*)d_in[2];
    const float* Wk    = (const float*)d_in[3];
    const float* bk    = (const float*)d_in[4];
    const float* Wv    = (const float*)d_in[5];
    const float* bv    = (const float*)d_in[6];
    const float* Wo    = (const float*)d_in[7];
    const float* bo    = (const float*)d_in[8];
    const float* gamma = (const float*)d_in[9];
    const float* beta  = (const float*)d_in[10];

    char* ws = (char*)d_ws;
    ushort* xb  = (ushort*)(ws);                       // 16 MB
    ushort* Wqb = (ushort*)(ws + (size_t)(16 << 20));  // 2 MB each
    ushort* Wkb = (ushort*)(ws + (size_t)(18 << 20));
    ushort* Wvb = (ushort*)(ws + (size_t)(20 << 20));
    ushort* Wob = (ushort*)(ws + (size_t)(22 << 20));
    ushort* Qb  = (ushort*)(ws + (size_t)(24 << 20));  // 16 MB (= ctx alias)
    ushort* Kb  = (ushort*)(ws + (size_t)(40 << 20));  // 16 MB
    ushort* Vt  = (ushort*)(ws + (size_t)(56 << 20));  // 16 MB
    float*  Xr  = (float*) (ws + (size_t)(40 << 20));  // 32 MB, aliases Kb+Vt (dead post-attn)

    cvt_all<<<12288, 256, 0, stream>>>((const float4*)x, (const float4*)Wq, (const float4*)Wk,
                                       (const float4*)Wv, (const float4*)Wo,
                                       (ushort4*)xb, (ushort4*)Wqb, (ushort4*)Wkb,
                                       (ushort4*)Wvb, (ushort4*)Wob);

    qkv_gemm<<<768, 512, 0, stream>>>(
        xb, Wqb, Wkb, Wvb, bq, bk, bv, Qb, Kb, Vt);

    flash_attn_mfma<<<BB * NH * (SS / 256), 256, 0, stream>>>(Qb, Kb, Vt, Qb /*ctx*/);

    oproj_gemm<<<256, 512, 0, stream>>>(Qb, Wob, bo, x, Xr);

    ln_kernel<<<M_ROWS, 256, 0, stream>>>(Xr, gamma, beta, (float*)d_out);
}